// Round 8
// baseline (1292.002 us; speedup 1.0000x reference)
//
#include <hip/hip_runtime.h>
#include <math.h>

#define NH 16
#define HD 64
#define DIM 1024
#define QKV_DIM 3072
#define MAXLEN 2048

// hardcoded problem constants (fixed by reference setup)
__device__ __constant__ int g_cu[5]  = {0, 2048, 3584, 4608, 5120};
__device__ __constant__ int g_seq[4] = {2048, 1536, 1024, 512};

// ---------------------------------------------------------------------------
// GEMM: C[M][N] = A[M][K] * B[N][K]^T   (both A,B row-major, K-contiguous)
// 128x128 tile, BK=16, 256 threads, 8x8 per thread, fp32.
// ---------------------------------------------------------------------------
__global__ __launch_bounds__(256) void gemm_abt(const float* __restrict__ A,
                                                const float* __restrict__ B,
                                                float* __restrict__ C,
                                                int M, int N, int K) {
    constexpr int BM = 128, BN = 128, BK = 16;
    __shared__ float As[BK][BM + 4];
    __shared__ float Bs[BK][BN + 4];

    const int tid = threadIdx.x;
    const int bm = blockIdx.y * BM;
    const int bn = blockIdx.x * BN;
    const int ty = tid / 16;
    const int tx = tid % 16;

    float acc[8][8] = {};

    for (int k0 = 0; k0 < K; k0 += BK) {
#pragma unroll
        for (int it = 0; it < 2; ++it) {
            int item = tid + it * 256;
            int r = item >> 2;
            int c4 = item & 3;
            float4 v = *(const float4*)&A[(size_t)(bm + r) * K + k0 + c4 * 4];
            As[c4 * 4 + 0][r] = v.x;
            As[c4 * 4 + 1][r] = v.y;
            As[c4 * 4 + 2][r] = v.z;
            As[c4 * 4 + 3][r] = v.w;
        }
#pragma unroll
        for (int it = 0; it < 2; ++it) {
            int item = tid + it * 256;
            int r = item >> 2;
            int c4 = item & 3;
            float4 v = *(const float4*)&B[(size_t)(bn + r) * K + k0 + c4 * 4];
            Bs[c4 * 4 + 0][r] = v.x;
            Bs[c4 * 4 + 1][r] = v.y;
            Bs[c4 * 4 + 2][r] = v.z;
            Bs[c4 * 4 + 3][r] = v.w;
        }
        __syncthreads();

#pragma unroll
        for (int k = 0; k < BK; ++k) {
            float a[8], b[8];
            *(float4*)&a[0] = *(const float4*)&As[k][ty * 8 + 0];
            *(float4*)&a[4] = *(const float4*)&As[k][ty * 8 + 4];
            *(float4*)&b[0] = *(const float4*)&Bs[k][tx * 8 + 0];
            *(float4*)&b[4] = *(const float4*)&Bs[k][tx * 8 + 4];
#pragma unroll
            for (int i = 0; i < 8; ++i)
#pragma unroll
                for (int j = 0; j < 8; ++j) acc[i][j] = fmaf(a[i], b[j], acc[i][j]);
        }
        __syncthreads();
    }

#pragma unroll
    for (int i = 0; i < 8; ++i) {
#pragma unroll
        for (int j = 0; j < 8; j += 4) {
            float4 v = {acc[i][j], acc[i][j + 1], acc[i][j + 2], acc[i][j + 3]};
            *(float4*)&C[(size_t)(bm + ty * 8 + i) * N + bn + tx * 8 + j] = v;
        }
    }
}

// ---------------------------------------------------------------------------
// RoPE in place on q and k halves of the unpadded qkv buffer.
// ---------------------------------------------------------------------------
__global__ __launch_bounds__(256) void rope_kernel(float* __restrict__ qkv, int total) {
    int id = blockIdx.x * blockDim.x + threadIdx.x;
    int nitems = total * NH * 32;
    if (id >= nitems) return;
    int j = id & 31;
    int h = (id >> 5) & (NH - 1);
    int row = id >> 9;

    int b = 0;
    while (row >= g_cu[b + 1]) b++;
    int pos = row - g_cu[b];

    float inv_freq = powf(10000.0f, -(float)(2 * j) / 64.0f);
    float fr = (float)pos * inv_freq;
    float c = cosf(fr), s = sinf(fr);

    float* base = qkv + (size_t)row * QKV_DIM + h * HD;
#pragma unroll
    for (int part = 0; part < 2; ++part) {
        float* p = base + part * DIM;
        float x1 = p[j];
        float x2 = p[j + 32];
        p[j] = x1 * c - x2 * s;
        p[j + 32] = x2 * c + x1 * s;
    }
}

// ---------------------------------------------------------------------------
// Attention v5: GEMM-structured flash attention (fp32 VALU), v4 + two fixes:
//  (1) P^T aliases the K^T buffer (K^T dead after QK^T; one extra barrier):
//      LDS 68.6 KB -> 51.2 KB -> 3 blocks/CU (v4 occupancy was 16.9%, LDS-
//      capped at 2 blocks, so barrier phases couldn't overlap across blocks).
//  (2) XOR quad-swizzle col ^= ((row>>3)&3)<<2 on the stride-68 transposed
//      buffers (Qt/KP). v4 had 4.05e7 LDS bank conflict cycles: with stride
//      68 = 4 dwords mod 32, each 16-lane phase of the P^T ds_write_b128 hit
//      only 2 start-bank quads (16*(tx&1)+4ty). The swizzle spreads start
//      quads over all 8 positions per phase; staging writes land 2-way (free).
//      Reads stay broadcast (a) / 2-way (b). Swizzle is 16B-granular so all
//      float4 accesses stay aligned.
// Block = 256 threads (16x16), one 64-query tile of one (batch,head); thread
// owns a 4x4 tile of scores/output. Softmax in exp2 domain (log2e folded into
// Q). Padded keys (score 0, v 0) add (MAXLEN-L)*2^(-m) to the denom only.
// ---------------------------------------------------------------------------
__global__ __launch_bounds__(256, 3) void attn_kernel(const float* __restrict__ qkv,
                                                      float* __restrict__ attn) {
    __shared__ float Qt[64 * 68];   // Q^T, swizzled
    __shared__ float KP[64 * 68];   // K^T during QK, P^T during PV, swizzled
    __shared__ float Vs[64][64];    // V row-major

    // blockIdx.x in [0,80): per-batch 64-row tile counts {32,24,16,8}.
    const int tiles_pref[5] = {0, 32, 56, 72, 80};
    int t = blockIdx.x;
    int b = 0;
    while (t >= tiles_pref[b + 1]) b++;
    const int qstart = (t - tiles_pref[b]) * 64;
    const int h = blockIdx.y;
    const int L = g_seq[b];
    const int base = g_cu[b];
    const int tid = threadIdx.x;
    const int ty = tid >> 4;   // 0..15: row group (4 query rows)
    const int tx = tid & 15;   // 0..15: col group (4 keys / 4 dims)
    const int tyo = ty * 4, txo = tx * 4;

    const float scale = 0.125f * 1.44269504088896f;  // 1/sqrt(64) * log2(e)

    // Stage Q transposed + scaled + swizzled: Qt[dim][qrow ^ sw]
#pragma unroll
    for (int it = 0; it < 4; ++it) {
        int item = tid + it * 256;
        int r = item >> 4, c4 = item & 15;     // r: q-row 0..63, c4: dim quad
        const float* src = qkv + (size_t)(base + qstart + r) * QKV_DIM + h * HD + c4 * 4;
        float4 v = *(const float4*)src;
        int col = r ^ (((c4 >> 1) & 3) << 2);  // ((row>>3)&3)<<2, row=4*c4+i
        Qt[(c4 * 4 + 0) * 68 + col] = v.x * scale;
        Qt[(c4 * 4 + 1) * 68 + col] = v.y * scale;
        Qt[(c4 * 4 + 2) * 68 + col] = v.z * scale;
        Qt[(c4 * 4 + 3) * 68 + col] = v.w * scale;
    }

    float o[4][4] = {};
    float m[4] = {-1e30f, -1e30f, -1e30f, -1e30f};
    float d[4] = {};

    for (int k0 = 0; k0 < L; k0 += 64) {
        __syncthreads();  // A: prev PV done reading KP(P^T)/Vs; Qt visible (1st)
        // stage K^T (swizzled) + V row-major
#pragma unroll
        for (int it = 0; it < 4; ++it) {
            int item = tid + it * 256;
            int r = item >> 4, c4 = item & 15;  // r: key 0..63, c4: dim quad
            const float* src = qkv + (size_t)(base + k0 + r) * QKV_DIM + DIM + h * HD + c4 * 4;
            float4 kv = *(const float4*)src;
            int col = r ^ (((c4 >> 1) & 3) << 2);
            KP[(c4 * 4 + 0) * 68 + col] = kv.x;
            KP[(c4 * 4 + 1) * 68 + col] = kv.y;
            KP[(c4 * 4 + 2) * 68 + col] = kv.z;
            KP[(c4 * 4 + 3) * 68 + col] = kv.w;
            *(float4*)&Vs[r][c4 * 4] = *(const float4*)(src + DIM);
        }
        __syncthreads();  // B: staged tiles visible

        // QK^T outer product: s[i][j] = scores rows tyo+i, cols txo+j
        float s[4][4] = {};
#pragma unroll
        for (int k8 = 0; k8 < 8; ++k8) {
            int sw = (k8 & 3) << 2;
            const float* qb = &Qt[(k8 * 8) * 68 + (tyo ^ sw)];
            const float* kb = &KP[(k8 * 8) * 68 + (txo ^ sw)];
#pragma unroll
            for (int kk = 0; kk < 8; ++kk) {
                float4 a = *(const float4*)&qb[kk * 68];
                float4 bb = *(const float4*)&kb[kk * 68];
                s[0][0] = fmaf(a.x, bb.x, s[0][0]);
                s[0][1] = fmaf(a.x, bb.y, s[0][1]);
                s[0][2] = fmaf(a.x, bb.z, s[0][2]);
                s[0][3] = fmaf(a.x, bb.w, s[0][3]);
                s[1][0] = fmaf(a.y, bb.x, s[1][0]);
                s[1][1] = fmaf(a.y, bb.y, s[1][1]);
                s[1][2] = fmaf(a.y, bb.z, s[1][2]);
                s[1][3] = fmaf(a.y, bb.w, s[1][3]);
                s[2][0] = fmaf(a.z, bb.x, s[2][0]);
                s[2][1] = fmaf(a.z, bb.y, s[2][1]);
                s[2][2] = fmaf(a.z, bb.z, s[2][2]);
                s[2][3] = fmaf(a.z, bb.w, s[2][3]);
                s[3][0] = fmaf(a.w, bb.x, s[3][0]);
                s[3][1] = fmaf(a.w, bb.y, s[3][1]);
                s[3][2] = fmaf(a.w, bb.z, s[3][2]);
                s[3][3] = fmaf(a.w, bb.w, s[3][3]);
            }
        }

        // online softmax per row (reduce across the 16-lane row group)
#pragma unroll
        for (int i = 0; i < 4; ++i) {
            float rmax = fmaxf(fmaxf(s[i][0], s[i][1]), fmaxf(s[i][2], s[i][3]));
            rmax = fmaxf(rmax, __shfl_xor(rmax, 1));
            rmax = fmaxf(rmax, __shfl_xor(rmax, 2));
            rmax = fmaxf(rmax, __shfl_xor(rmax, 4));
            rmax = fmaxf(rmax, __shfl_xor(rmax, 8));
            float mn = fmaxf(m[i], rmax);
            float corr = exp2f(m[i] - mn);
            m[i] = mn;
            float p0 = exp2f(s[i][0] - mn);
            float p1 = exp2f(s[i][1] - mn);
            float p2 = exp2f(s[i][2] - mn);
            float p3 = exp2f(s[i][3] - mn);
            float ps = (p0 + p1) + (p2 + p3);
            ps += __shfl_xor(ps, 1);
            ps += __shfl_xor(ps, 2);
            ps += __shfl_xor(ps, 4);
            ps += __shfl_xor(ps, 8);
            d[i] = d[i] * corr + ps;
            o[i][0] *= corr; o[i][1] *= corr; o[i][2] *= corr; o[i][3] *= corr;
            s[i][0] = p0; s[i][1] = p1; s[i][2] = p2; s[i][3] = p3;
        }

        __syncthreads();  // C: all QK reads of KP done before P^T overwrite

        // write P^T into KP (swizzled): row = key txo+j, col = tyo
        {
            int swp = ((tx >> 1) & 3) << 2;   // ((row>>3)&3)<<2, row=4*tx+j
#pragma unroll
            for (int j = 0; j < 4; ++j) {
                float4 pv = {s[0][j], s[1][j], s[2][j], s[3][j]};
                *(float4*)&KP[(txo + j) * 68 + (tyo ^ swp)] = pv;
            }
        }
        __syncthreads();  // D: P^T visible

        // PV outer product: o[i][j] += sum_kk P[tyo+i][kk] * V[kk][txo+j]
#pragma unroll
        for (int k8 = 0; k8 < 8; ++k8) {
            int sw = (k8 & 3) << 2;
            const float* pb = &KP[(k8 * 8) * 68 + (tyo ^ sw)];
#pragma unroll
            for (int kk = 0; kk < 8; ++kk) {
                float4 a = *(const float4*)&pb[kk * 68];
                float4 bb = *(const float4*)&Vs[k8 * 8 + kk][txo];
                o[0][0] = fmaf(a.x, bb.x, o[0][0]);
                o[0][1] = fmaf(a.x, bb.y, o[0][1]);
                o[0][2] = fmaf(a.x, bb.z, o[0][2]);
                o[0][3] = fmaf(a.x, bb.w, o[0][3]);
                o[1][0] = fmaf(a.y, bb.x, o[1][0]);
                o[1][1] = fmaf(a.y, bb.y, o[1][1]);
                o[1][2] = fmaf(a.y, bb.z, o[1][2]);
                o[1][3] = fmaf(a.y, bb.w, o[1][3]);
                o[2][0] = fmaf(a.z, bb.x, o[2][0]);
                o[2][1] = fmaf(a.z, bb.y, o[2][1]);
                o[2][2] = fmaf(a.z, bb.z, o[2][2]);
                o[2][3] = fmaf(a.z, bb.w, o[2][3]);
                o[3][0] = fmaf(a.w, bb.x, o[3][0]);
                o[3][1] = fmaf(a.w, bb.y, o[3][1]);
                o[3][2] = fmaf(a.w, bb.z, o[3][2]);
                o[3][3] = fmaf(a.w, bb.w, o[3][3]);
            }
        }
    }

    // padded keys: score 0 (in exp2-scaled domain too), v 0 -> denom only
    int npad = MAXLEN - L;
    if (npad) {
#pragma unroll
        for (int i = 0; i < 4; ++i) d[i] += (float)npad * exp2f(0.0f - m[i]);
    }

    // write output: rows qstart+tyo+i, dims h*64 + txo..+4
#pragma unroll
    for (int i = 0; i < 4; ++i) {
        float inv = 1.0f / d[i];
        float4 v = {o[i][0] * inv, o[i][1] * inv, o[i][2] * inv, o[i][3] * inv};
        *(float4*)&attn[(size_t)(base + qstart + tyo + i) * DIM + h * HD + txo] = v;
    }
}

// ---------------------------------------------------------------------------
extern "C" void kernel_launch(void* const* d_in, const int* in_sizes, int n_in,
                              void* d_out, int out_size, void* d_ws, size_t ws_size,
                              hipStream_t stream) {
    const float* hidden = (const float*)d_in[0];
    const float* Wqkv = (const float*)d_in[1];
    const float* Wo = (const float*)d_in[2];
    float* out = (float*)d_out;

    const int total = in_sizes[0] / DIM;  // 5120

    float* qkv = (float*)d_ws;                        // total * 3072
    float* attn = qkv + (size_t)total * QKV_DIM;      // total * 1024

    // 1) qkv = hidden @ Wqkv^T   (5120 x 3072, K=1024)
    gemm_abt<<<dim3(QKV_DIM / 128, total / 128), 256, 0, stream>>>(
        hidden, Wqkv, qkv, total, QKV_DIM, DIM);

    // 2) RoPE in place on q,k
    int nitems = total * NH * 32;
    rope_kernel<<<(nitems + 255) / 256, 256, 0, stream>>>(qkv, total);

    // 3) attention -> attn buffer
    attn_kernel<<<dim3(80, NH), 256, 0, stream>>>(qkv, attn);

    // 4) out = attn @ Wo^T       (5120 x 1024, K=1024)
    gemm_abt<<<dim3(DIM / 128, total / 128), 256, 0, stream>>>(
        attn, Wo, out, total, DIM, DIM);
}

// Round 10
// 911.375 us; speedup vs baseline: 1.4176x; 1.4176x over previous
//
#include <hip/hip_runtime.h>
#include <math.h>

#define NH 16
#define HD 64
#define DIM 1024
#define QKV_DIM 3072
#define MAXLEN 2048

typedef unsigned short ushort_t;
typedef unsigned int uint_t;
typedef __attribute__((ext_vector_type(8))) short bf16x8;
typedef __attribute__((ext_vector_type(8))) unsigned short ushort8;
typedef __attribute__((ext_vector_type(4))) float f32x4;

// hardcoded problem constants (fixed by reference setup)
__device__ __constant__ int g_cu[5]  = {0, 2048, 3584, 4608, 5120};
__device__ __constant__ int g_seq[4] = {2048, 1536, 1024, 512};

// ---------------------------------------------------------------------------
// Split fp32 -> (hi, lo) bf16 pair.  x ~= bf2f(hi) + bf2f(lo), |err| ~ 2^-17|x|
// ---------------------------------------------------------------------------
__device__ inline ushort_t f2bf(float f) {
    uint_t u = __float_as_uint(f);
    uint_t r = u + 0x7FFFu + ((u >> 16) & 1u);   // RNE
    return (ushort_t)(r >> 16);
}
__device__ inline float bf2f(ushort_t h) { return __uint_as_float(((uint_t)h) << 16); }

__global__ __launch_bounds__(256) void split_bf16(const float* __restrict__ x,
                                                  ushort_t* __restrict__ hi,
                                                  ushort_t* __restrict__ lo, int n4) {
    int i = blockIdx.x * 256 + threadIdx.x;
    if (i >= n4) return;
    float4 v = ((const float4*)x)[i];
    ushort_t h0 = f2bf(v.x), h1 = f2bf(v.y), h2 = f2bf(v.z), h3 = f2bf(v.w);
    ushort_t l0 = f2bf(v.x - bf2f(h0));
    ushort_t l1 = f2bf(v.y - bf2f(h1));
    ushort_t l2 = f2bf(v.z - bf2f(h2));
    ushort_t l3 = f2bf(v.w - bf2f(h3));
    ushort4 hv = {h0, h1, h2, h3};
    ushort4 lv = {l0, l1, l2, l3};
    ((ushort4*)hi)[i] = hv;
    ((ushort4*)lo)[i] = lv;
}

// ---------------------------------------------------------------------------
// Split-bf16 MFMA GEMM: C[M][N] = A[M][K] * B[N][K]^T, fp32-accurate via
// 3-term Markidis split (ah*bh + ah*bl + al*bh; dropped al*bl ~ 2^-17 rel).
// 128x128 tile, BK=32, 256 threads = 4 waves (2x2), each wave owns 64x64 =
// 4x4 fragments of mfma_f32_16x16x32_bf16. Per K-tile per wave: 16
// ds_read_b128 feed 48 MFMAs. Reg-staged LDS (16B/thread x 2 passes / tile).
// Fragment layout (cdna4 guide, HW-verified m89/m91): A lane l holds
// A[l&15][(l>>4)*8+j]; B lane l holds B[k=(l>>4)*8+j][col=l&15] = Bmat[l&15][k];
// D lane l reg r -> row (l>>4)*4+r, col l&15.
// ---------------------------------------------------------------------------
__global__ __launch_bounds__(256) void gemm_mfma_split(
    const ushort_t* __restrict__ Ah, const ushort_t* __restrict__ Al,
    const ushort_t* __restrict__ Bh, const ushort_t* __restrict__ Bl,
    float* __restrict__ C, int M, int N, int K) {
    __shared__ ushort_t sAh[128 * 32], sAl[128 * 32];
    __shared__ ushort_t sBh[128 * 32], sBl[128 * 32];

    const int tid = threadIdx.x;
    const int lane = tid & 63;
    const int w = tid >> 6;                 // wave 0..3
    const int bm = blockIdx.y * 128, bn = blockIdx.x * 128;
    const int wm = (w >> 1) * 64, wn = (w & 1) * 64;

    f32x4 acc[4][4] = {};

    const int srow = tid >> 2;              // 0..63 staging row (per pass)
    const int scol = (tid & 3) * 8;         // 0,8,16,24

    for (int k0 = 0; k0 < K; k0 += 32) {
        __syncthreads();   // previous compute done reading LDS
#pragma unroll
        for (int i = 0; i < 2; ++i) {
            int r = i * 64 + srow;
            size_t ga = (size_t)(bm + r) * K + k0 + scol;
            size_t gb = (size_t)(bn + r) * K + k0 + scol;
            int ls = r * 32 + scol;
            *(ushort8*)&sAh[ls] = *(const ushort8*)&Ah[ga];
            *(ushort8*)&sAl[ls] = *(const ushort8*)&Al[ga];
            *(ushort8*)&sBh[ls] = *(const ushort8*)&Bh[gb];
            *(ushort8*)&sBl[ls] = *(const ushort8*)&Bl[gb];
        }
        __syncthreads();   // staged tiles visible

        const int frow = lane & 15;
        const int fk = (lane >> 4) * 8;
        bf16x8 ah[4], al[4], bh[4], bl[4];
#pragma unroll
        for (int t = 0; t < 4; ++t) {
            int ar = (wm + t * 16 + frow) * 32 + fk;
            int br = (wn + t * 16 + frow) * 32 + fk;
            ah[t] = *(const bf16x8*)&sAh[ar];
            al[t] = *(const bf16x8*)&sAl[ar];
            bh[t] = *(const bf16x8*)&sBh[br];
            bl[t] = *(const bf16x8*)&sBl[br];
        }
#pragma unroll
        for (int mt = 0; mt < 4; ++mt)
#pragma unroll
            for (int nt = 0; nt < 4; ++nt) {
                acc[mt][nt] = __builtin_amdgcn_mfma_f32_16x16x32_bf16(ah[mt], bh[nt], acc[mt][nt], 0, 0, 0);
                acc[mt][nt] = __builtin_amdgcn_mfma_f32_16x16x32_bf16(ah[mt], bl[nt], acc[mt][nt], 0, 0, 0);
                acc[mt][nt] = __builtin_amdgcn_mfma_f32_16x16x32_bf16(al[mt], bh[nt], acc[mt][nt], 0, 0, 0);
            }
    }

    const int crow0 = (lane >> 4) * 4;
    const int ccol = lane & 15;
#pragma unroll
    for (int mt = 0; mt < 4; ++mt)
#pragma unroll
        for (int nt = 0; nt < 4; ++nt) {
            size_t rbase = (size_t)(bm + wm + mt * 16 + crow0) * N + bn + wn + nt * 16 + ccol;
#pragma unroll
            for (int r = 0; r < 4; ++r)
                C[rbase + (size_t)r * N] = acc[mt][nt][r];
        }
}

// ---------------------------------------------------------------------------
// RoPE in place on q and k halves of the unpadded qkv buffer.
// ---------------------------------------------------------------------------
__global__ __launch_bounds__(256) void rope_kernel(float* __restrict__ qkv, int total) {
    int id = blockIdx.x * blockDim.x + threadIdx.x;
    int nitems = total * NH * 32;
    if (id >= nitems) return;
    int j = id & 31;
    int h = (id >> 5) & (NH - 1);
    int row = id >> 9;

    int b = 0;
    while (row >= g_cu[b + 1]) b++;
    int pos = row - g_cu[b];

    float inv_freq = powf(10000.0f, -(float)(2 * j) / 64.0f);
    float fr = (float)pos * inv_freq;
    float c = cosf(fr), s = sinf(fr);

    float* base = qkv + (size_t)row * QKV_DIM + h * HD;
#pragma unroll
    for (int part = 0; part < 2; ++part) {
        float* p = base + part * DIM;
        float x1 = p[j];
        float x2 = p[j + 32];
        p[j] = x1 * c - x2 * s;
        p[j + 32] = x2 * c + x1 * s;
    }
}

// ---------------------------------------------------------------------------
// Attention v5 (unchanged from round 6/8): GEMM-structured fp32 flash attn.
// Known state: 707 us, LDS-issue-bound (VALUBusy 59%, conflicts 4.1e6).
// Next structural step for this kernel is split-bf16 MFMA (pending GEMM proof).
// ---------------------------------------------------------------------------
__global__ __launch_bounds__(256, 3) void attn_kernel(const float* __restrict__ qkv,
                                                      float* __restrict__ attn) {
    __shared__ float Qt[64 * 68];   // Q^T, swizzled
    __shared__ float KP[64 * 68];   // K^T during QK, P^T during PV, swizzled
    __shared__ float Vs[64][64];    // V row-major

    const int tiles_pref[5] = {0, 32, 56, 72, 80};
    int t = blockIdx.x;
    int b = 0;
    while (t >= tiles_pref[b + 1]) b++;
    const int qstart = (t - tiles_pref[b]) * 64;
    const int h = blockIdx.y;
    const int L = g_seq[b];
    const int base = g_cu[b];
    const int tid = threadIdx.x;
    const int ty = tid >> 4;
    const int tx = tid & 15;
    const int tyo = ty * 4, txo = tx * 4;

    const float scale = 0.125f * 1.44269504088896f;  // 1/sqrt(64) * log2(e)

#pragma unroll
    for (int it = 0; it < 4; ++it) {
        int item = tid + it * 256;
        int r = item >> 4, c4 = item & 15;
        const float* src = qkv + (size_t)(base + qstart + r) * QKV_DIM + h * HD + c4 * 4;
        float4 v = *(const float4*)src;
        int col = r ^ (((c4 >> 1) & 3) << 2);
        Qt[(c4 * 4 + 0) * 68 + col] = v.x * scale;
        Qt[(c4 * 4 + 1) * 68 + col] = v.y * scale;
        Qt[(c4 * 4 + 2) * 68 + col] = v.z * scale;
        Qt[(c4 * 4 + 3) * 68 + col] = v.w * scale;
    }

    float o[4][4] = {};
    float m[4] = {-1e30f, -1e30f, -1e30f, -1e30f};
    float d[4] = {};

    for (int k0 = 0; k0 < L; k0 += 64) {
        __syncthreads();
#pragma unroll
        for (int it = 0; it < 4; ++it) {
            int item = tid + it * 256;
            int r = item >> 4, c4 = item & 15;
            const float* src = qkv + (size_t)(base + k0 + r) * QKV_DIM + DIM + h * HD + c4 * 4;
            float4 kv = *(const float4*)src;
            int col = r ^ (((c4 >> 1) & 3) << 2);
            KP[(c4 * 4 + 0) * 68 + col] = kv.x;
            KP[(c4 * 4 + 1) * 68 + col] = kv.y;
            KP[(c4 * 4 + 2) * 68 + col] = kv.z;
            KP[(c4 * 4 + 3) * 68 + col] = kv.w;
            *(float4*)&Vs[r][c4 * 4] = *(const float4*)(src + DIM);
        }
        __syncthreads();

        float s[4][4] = {};
#pragma unroll
        for (int k8 = 0; k8 < 8; ++k8) {
            int sw = (k8 & 3) << 2;
            const float* qb = &Qt[(k8 * 8) * 68 + (tyo ^ sw)];
            const float* kb = &KP[(k8 * 8) * 68 + (txo ^ sw)];
#pragma unroll
            for (int kk = 0; kk < 8; ++kk) {
                float4 a = *(const float4*)&qb[kk * 68];
                float4 bb = *(const float4*)&kb[kk * 68];
                s[0][0] = fmaf(a.x, bb.x, s[0][0]);
                s[0][1] = fmaf(a.x, bb.y, s[0][1]);
                s[0][2] = fmaf(a.x, bb.z, s[0][2]);
                s[0][3] = fmaf(a.x, bb.w, s[0][3]);
                s[1][0] = fmaf(a.y, bb.x, s[1][0]);
                s[1][1] = fmaf(a.y, bb.y, s[1][1]);
                s[1][2] = fmaf(a.y, bb.z, s[1][2]);
                s[1][3] = fmaf(a.y, bb.w, s[1][3]);
                s[2][0] = fmaf(a.z, bb.x, s[2][0]);
                s[2][1] = fmaf(a.z, bb.y, s[2][1]);
                s[2][2] = fmaf(a.z, bb.z, s[2][2]);
                s[2][3] = fmaf(a.z, bb.w, s[2][3]);
                s[3][0] = fmaf(a.w, bb.x, s[3][0]);
                s[3][1] = fmaf(a.w, bb.y, s[3][1]);
                s[3][2] = fmaf(a.w, bb.z, s[3][2]);
                s[3][3] = fmaf(a.w, bb.w, s[3][3]);
            }
        }

#pragma unroll
        for (int i = 0; i < 4; ++i) {
            float rmax = fmaxf(fmaxf(s[i][0], s[i][1]), fmaxf(s[i][2], s[i][3]));
            rmax = fmaxf(rmax, __shfl_xor(rmax, 1));
            rmax = fmaxf(rmax, __shfl_xor(rmax, 2));
            rmax = fmaxf(rmax, __shfl_xor(rmax, 4));
            rmax = fmaxf(rmax, __shfl_xor(rmax, 8));
            float mn = fmaxf(m[i], rmax);
            float corr = exp2f(m[i] - mn);
            m[i] = mn;
            float p0 = exp2f(s[i][0] - mn);
            float p1 = exp2f(s[i][1] - mn);
            float p2 = exp2f(s[i][2] - mn);
            float p3 = exp2f(s[i][3] - mn);
            float ps = (p0 + p1) + (p2 + p3);
            ps += __shfl_xor(ps, 1);
            ps += __shfl_xor(ps, 2);
            ps += __shfl_xor(ps, 4);
            ps += __shfl_xor(ps, 8);
            d[i] = d[i] * corr + ps;
            o[i][0] *= corr; o[i][1] *= corr; o[i][2] *= corr; o[i][3] *= corr;
            s[i][0] = p0; s[i][1] = p1; s[i][2] = p2; s[i][3] = p3;
        }

        __syncthreads();

        {
            int swp = ((tx >> 1) & 3) << 2;
#pragma unroll
            for (int j = 0; j < 4; ++j) {
                float4 pv = {s[0][j], s[1][j], s[2][j], s[3][j]};
                *(float4*)&KP[(txo + j) * 68 + (tyo ^ swp)] = pv;
            }
        }
        __syncthreads();

#pragma unroll
        for (int k8 = 0; k8 < 8; ++k8) {
            int sw = (k8 & 3) << 2;
            const float* pb = &KP[(k8 * 8) * 68 + (tyo ^ sw)];
#pragma unroll
            for (int kk = 0; kk < 8; ++kk) {
                float4 a = *(const float4*)&pb[kk * 68];
                float4 bb = *(const float4*)&Vs[k8 * 8 + kk][txo];
                o[0][0] = fmaf(a.x, bb.x, o[0][0]);
                o[0][1] = fmaf(a.x, bb.y, o[0][1]);
                o[0][2] = fmaf(a.x, bb.z, o[0][2]);
                o[0][3] = fmaf(a.x, bb.w, o[0][3]);
                o[1][0] = fmaf(a.y, bb.x, o[1][0]);
                o[1][1] = fmaf(a.y, bb.y, o[1][1]);
                o[1][2] = fmaf(a.y, bb.z, o[1][2]);
                o[1][3] = fmaf(a.y, bb.w, o[1][3]);
                o[2][0] = fmaf(a.z, bb.x, o[2][0]);
                o[2][1] = fmaf(a.z, bb.y, o[2][1]);
                o[2][2] = fmaf(a.z, bb.z, o[2][2]);
                o[2][3] = fmaf(a.z, bb.w, o[2][3]);
                o[3][0] = fmaf(a.w, bb.x, o[3][0]);
                o[3][1] = fmaf(a.w, bb.y, o[3][1]);
                o[3][2] = fmaf(a.w, bb.z, o[3][2]);
                o[3][3] = fmaf(a.w, bb.w, o[3][3]);
            }
        }
    }

    int npad = MAXLEN - L;
    if (npad) {
#pragma unroll
        for (int i = 0; i < 4; ++i) d[i] += (float)npad * exp2f(0.0f - m[i]);
    }

#pragma unroll
    for (int i = 0; i < 4; ++i) {
        float inv = 1.0f / d[i];
        float4 v = {o[i][0] * inv, o[i][1] * inv, o[i][2] * inv, o[i][3] * inv};
        *(float4*)&attn[(size_t)(base + qstart + tyo + i) * DIM + h * HD + txo] = v;
    }
}

// ---------------------------------------------------------------------------
extern "C" void kernel_launch(void* const* d_in, const int* in_sizes, int n_in,
                              void* d_out, int out_size, void* d_ws, size_t ws_size,
                              hipStream_t stream) {
    const float* hidden = (const float*)d_in[0];
    const float* Wqkv = (const float*)d_in[1];
    const float* Wo = (const float*)d_in[2];
    float* out = (float*)d_out;

    const int total = in_sizes[0] / DIM;  // 5120

    // workspace layout
    float* qkv = (float*)d_ws;                           // total*3072 f32
    float* attnb = qkv + (size_t)total * QKV_DIM;        // total*1024 f32
    ushort_t* us = (ushort_t*)(attnb + (size_t)total * DIM);
    const size_t nh = (size_t)total * DIM;               // 5.24M
    const size_t nw = (size_t)QKV_DIM * DIM;             // 3.15M
    const size_t no = (size_t)DIM * DIM;                 // 1.05M
    ushort_t* h_hi = us;            ushort_t* h_lo = h_hi + nh;
    ushort_t* wq_hi = h_lo + nh;    ushort_t* wq_lo = wq_hi + nw;
    ushort_t* ao_hi = wq_lo + nw;   ushort_t* ao_lo = ao_hi + nh;
    ushort_t* wo_hi = ao_lo + nh;   ushort_t* wo_lo = wo_hi + no;

    // 0) split inputs to bf16 hi/lo
    split_bf16<<<(int)(nh / 4 + 255) / 256, 256, 0, stream>>>(hidden, h_hi, h_lo, (int)(nh / 4));
    split_bf16<<<(int)(nw / 4 + 255) / 256, 256, 0, stream>>>(Wqkv, wq_hi, wq_lo, (int)(nw / 4));
    split_bf16<<<(int)(no / 4 + 255) / 256, 256, 0, stream>>>(Wo, wo_hi, wo_lo, (int)(no / 4));

    // 1) qkv = hidden @ Wqkv^T  (M=5120, N=3072, K=1024), split-bf16 MFMA
    gemm_mfma_split<<<dim3(QKV_DIM / 128, total / 128), 256, 0, stream>>>(
        h_hi, h_lo, wq_hi, wq_lo, qkv, total, QKV_DIM, DIM);

    // 2) RoPE in place on q,k
    int nitems = total * NH * 32;
    rope_kernel<<<(nitems + 255) / 256, 256, 0, stream>>>(qkv, total);

    // 3) attention -> attnb
    attn_kernel<<<dim3(80, NH), 256, 0, stream>>>(qkv, attnb);

    // 4) split attention output, then out = attnb @ Wo^T
    split_bf16<<<(int)(nh / 4 + 255) / 256, 256, 0, stream>>>(attnb, ao_hi, ao_lo, (int)(nh / 4));
    gemm_mfma_split<<<dim3(DIM / 128, total / 128), 256, 0, stream>>>(
        ao_hi, ao_lo, wo_hi, wo_lo, out, total, DIM, DIM);
}

// Round 11
// 580.525 us; speedup vs baseline: 2.2256x; 1.5699x over previous
//
#include <hip/hip_runtime.h>
#include <math.h>

#define NH 16
#define HD 64
#define DIM 1024
#define QKV_DIM 3072
#define MAXLEN 2048
#define TOTAL 5120

typedef unsigned short ushort_t;
typedef unsigned int uint_t;
typedef __attribute__((ext_vector_type(8))) short bf16x8;
typedef __attribute__((ext_vector_type(8))) unsigned short ushort8;
typedef __attribute__((ext_vector_type(4))) float f32x4;

// hardcoded problem constants (fixed by reference setup)
__device__ __constant__ int g_cu[5]  = {0, 2048, 3584, 4608, 5120};
__device__ __constant__ int g_seq[4] = {2048, 1536, 1024, 512};

// ---------------------------------------------------------------------------
// fp32 -> (hi, lo) bf16 pair. x ~= bf2f(hi)+bf2f(lo), |err| ~ 2^-17 |x|
// ---------------------------------------------------------------------------
__device__ inline ushort_t f2bf(float f) {
    uint_t u = __float_as_uint(f);
    uint_t r = u + 0x7FFFu + ((u >> 16) & 1u);   // RNE
    return (ushort_t)(r >> 16);
}
__device__ inline float bf2f(ushort_t h) { return __uint_as_float(((uint_t)h) << 16); }

__global__ __launch_bounds__(256) void split_bf16(const float* __restrict__ x,
                                                  ushort_t* __restrict__ hi,
                                                  ushort_t* __restrict__ lo, int n4) {
    int i = blockIdx.x * 256 + threadIdx.x;
    if (i >= n4) return;
    float4 v = ((const float4*)x)[i];
    ushort_t h0 = f2bf(v.x), h1 = f2bf(v.y), h2 = f2bf(v.z), h3 = f2bf(v.w);
    ushort_t l0 = f2bf(v.x - bf2f(h0));
    ushort_t l1 = f2bf(v.y - bf2f(h1));
    ushort_t l2 = f2bf(v.z - bf2f(h2));
    ushort_t l3 = f2bf(v.w - bf2f(h3));
    ushort4 hv = {h0, h1, h2, h3};
    ushort4 lv = {l0, l1, l2, l3};
    ((ushort4*)hi)[i] = hv;
    ((ushort4*)lo)[i] = lv;
}

// ---------------------------------------------------------------------------
// Split-bf16 MFMA GEMM (unchanged from round 10 — verified): C = A * B^T.
// ---------------------------------------------------------------------------
__global__ __launch_bounds__(256) void gemm_mfma_split(
    const ushort_t* __restrict__ Ah, const ushort_t* __restrict__ Al,
    const ushort_t* __restrict__ Bh, const ushort_t* __restrict__ Bl,
    float* __restrict__ C, int M, int N, int K) {
    __shared__ ushort_t sAh[128 * 32], sAl[128 * 32];
    __shared__ ushort_t sBh[128 * 32], sBl[128 * 32];

    const int tid = threadIdx.x;
    const int lane = tid & 63;
    const int w = tid >> 6;
    const int bm = blockIdx.y * 128, bn = blockIdx.x * 128;
    const int wm = (w >> 1) * 64, wn = (w & 1) * 64;

    f32x4 acc[4][4] = {};

    const int srow = tid >> 2;
    const int scol = (tid & 3) * 8;

    for (int k0 = 0; k0 < K; k0 += 32) {
        __syncthreads();
#pragma unroll
        for (int i = 0; i < 2; ++i) {
            int r = i * 64 + srow;
            size_t ga = (size_t)(bm + r) * K + k0 + scol;
            size_t gb = (size_t)(bn + r) * K + k0 + scol;
            int ls = r * 32 + scol;
            *(ushort8*)&sAh[ls] = *(const ushort8*)&Ah[ga];
            *(ushort8*)&sAl[ls] = *(const ushort8*)&Al[ga];
            *(ushort8*)&sBh[ls] = *(const ushort8*)&Bh[gb];
            *(ushort8*)&sBl[ls] = *(const ushort8*)&Bl[gb];
        }
        __syncthreads();

        const int frow = lane & 15;
        const int fk = (lane >> 4) * 8;
        bf16x8 ah[4], al[4], bh[4], bl[4];
#pragma unroll
        for (int t = 0; t < 4; ++t) {
            int ar = (wm + t * 16 + frow) * 32 + fk;
            int br = (wn + t * 16 + frow) * 32 + fk;
            ah[t] = *(const bf16x8*)&sAh[ar];
            al[t] = *(const bf16x8*)&sAl[ar];
            bh[t] = *(const bf16x8*)&sBh[br];
            bl[t] = *(const bf16x8*)&sBl[br];
        }
#pragma unroll
        for (int mt = 0; mt < 4; ++mt)
#pragma unroll
            for (int nt = 0; nt < 4; ++nt) {
                acc[mt][nt] = __builtin_amdgcn_mfma_f32_16x16x32_bf16(ah[mt], bh[nt], acc[mt][nt], 0, 0, 0);
                acc[mt][nt] = __builtin_amdgcn_mfma_f32_16x16x32_bf16(ah[mt], bl[nt], acc[mt][nt], 0, 0, 0);
                acc[mt][nt] = __builtin_amdgcn_mfma_f32_16x16x32_bf16(al[mt], bh[nt], acc[mt][nt], 0, 0, 0);
            }
    }

    const int crow0 = (lane >> 4) * 4;
    const int ccol = lane & 15;
#pragma unroll
    for (int mt = 0; mt < 4; ++mt)
#pragma unroll
        for (int nt = 0; nt < 4; ++nt) {
            size_t rbase = (size_t)(bm + wm + mt * 16 + crow0) * N + bn + wn + nt * 16 + ccol;
#pragma unroll
            for (int r = 0; r < 4; ++r)
                C[rbase + (size_t)r * N] = acc[mt][nt][r];
        }
}

// ---------------------------------------------------------------------------
// Pre-pass: K rope+split -> kh/kl [token][NH*64] bf16; V split+transpose ->
// vth/vtl [head][dim][token] bf16 (so attn's PV B-frags read contiguous keys).
// Block = 64 tokens x 1 head, grid (80, 16).
// ---------------------------------------------------------------------------
__global__ __launch_bounds__(256) void rope_split_kv(
    const float* __restrict__ qkv,
    ushort_t* __restrict__ kh, ushort_t* __restrict__ kl,
    ushort_t* __restrict__ vth, ushort_t* __restrict__ vtl) {
    __shared__ float tv[64][65];

    const int tiles_pref[5] = {0, 32, 56, 72, 80};
    int t = blockIdx.x;
    int b = 0;
    while (t >= tiles_pref[b + 1]) b++;
    const int t0 = (t - tiles_pref[b]) * 64;
    const int base = g_cu[b];
    const int h = blockIdx.y;
    const int tid = threadIdx.x;

    // ---- K: rope + split (pair j <-> j+32, j in 0..31) ----
    {
        int r = tid >> 2, jg = tid & 3;          // token row, dim-octet 8*jg..
        int tok = base + t0 + r;
        const float* kp = qkv + (size_t)tok * QKV_DIM + DIM + h * HD;
        float x1[8], x2[8];
        *(float4*)&x1[0] = *(const float4*)&kp[8 * jg + 0];
        *(float4*)&x1[4] = *(const float4*)&kp[8 * jg + 4];
        *(float4*)&x2[0] = *(const float4*)&kp[32 + 8 * jg + 0];
        *(float4*)&x2[4] = *(const float4*)&kp[32 + 8 * jg + 4];
        float pos = (float)(t0 + r);
        ushort8 h0v, l0v, h1v, l1v;
#pragma unroll
        for (int jj = 0; jj < 8; ++jj) {
            int j = 8 * jg + jj;
            float invf = powf(10000.0f, -(float)j / 32.0f);
            float sn, cs;
            sincosf(pos * invf, &sn, &cs);
            float y0 = x1[jj] * cs - x2[jj] * sn;
            float y1 = x2[jj] * cs + x1[jj] * sn;
            ushort_t hh = f2bf(y0);
            h0v[jj] = hh; l0v[jj] = f2bf(y0 - bf2f(hh));
            hh = f2bf(y1);
            h1v[jj] = hh; l1v[jj] = f2bf(y1 - bf2f(hh));
        }
        size_t o0 = (size_t)tok * DIM + h * HD + 8 * jg;
        *(ushort8*)&kh[o0] = h0v;      *(ushort8*)&kh[o0 + 32] = h1v;
        *(ushort8*)&kl[o0] = l0v;      *(ushort8*)&kl[o0 + 32] = l1v;
    }

    // ---- V: coalesced load -> LDS transpose -> split + transposed write ----
#pragma unroll
    for (int it = 0; it < 4; ++it) {
        int item = tid + it * 256;
        int r = item >> 4, c4 = item & 15;
        *(float4*)&tv[r][c4 * 4] =
            *(const float4*)(qkv + (size_t)(base + t0 + r) * QKV_DIM + 2 * DIM + h * HD + c4 * 4);
    }
    __syncthreads();
#pragma unroll
    for (int it = 0; it < 2; ++it) {
        int chunk = tid + it * 256;
        int dd = chunk >> 3, tb = chunk & 7;     // dim row, token-octet
        ushort8 vh, vl;
#pragma unroll
        for (int i = 0; i < 8; ++i) {
            float f = tv[tb * 8 + i][dd];
            ushort_t hh = f2bf(f);
            vh[i] = hh; vl[i] = f2bf(f - bf2f(hh));
        }
        size_t off = (size_t)(h * HD + dd) * TOTAL + base + t0 + tb * 8;
        *(ushort8*)&vth[off] = vh;
        *(ushort8*)&vtl[off] = vl;
    }
}

// ---------------------------------------------------------------------------
// Attention v6: split-bf16 MFMA flash attention.
// Block = 64 q-rows x one (batch,head); 4 waves, wave owns 16 q-rows.
// Per 64-key tile: stage K/V hi/lo to LDS (XOR-block swizzle: slot = blk ^
// (row&7), floor-rate b128 reads); QK^T = 24 mfma_16x16x32_bf16 (3-term
// split); softmax on the D-layout (row 4g+r, shfl 1/2/4/8 over c-lanes);
// P split -> per-wave LDS [16][72]us (144B stride: conflict-free b16 writes,
// 16B-aligned b128 A-frag reads); PV = 24 MFMA. Q rope+split in-reg at block
// start (scale*log2e folded into Q). Padded keys add npad*2^(-m) to denom.
// LDS 51.2 KB -> 3 blocks/CU. Fragment indexing mirrors gemm_mfma_split
// (verified on-device, round 10).
// ---------------------------------------------------------------------------
__global__ __launch_bounds__(256) void attn_mfma(
    const float* __restrict__ qkv,
    const ushort_t* __restrict__ kh, const ushort_t* __restrict__ kl,
    const ushort_t* __restrict__ vth, const ushort_t* __restrict__ vtl,
    float* __restrict__ attnb) {
    __shared__ ushort_t sKh[64 * 64], sKl[64 * 64];
    __shared__ ushort_t sVh[64 * 64], sVl[64 * 64];
    __shared__ ushort_t sPh[4][16 * 72], sPl[4][16 * 72];

    const int tiles_pref[5] = {0, 32, 56, 72, 80};
    int t = blockIdx.x;
    int b = 0;
    while (t >= tiles_pref[b + 1]) b++;
    const int qstart = (t - tiles_pref[b]) * 64;
    const int h = blockIdx.y;
    const int L = g_seq[b];
    const int base = g_cu[b];
    const int tid = threadIdx.x;
    const int lane = tid & 63;
    const int w = tid >> 6;      // wave 0..3: owns q-rows 16w..16w+15
    const int c = lane & 15;     // fragment row/col lane index
    const int g = lane >> 4;     // fragment k-group

    // ---- Q: rope + scale + split into A-fragments (registers) ----
    const float SCALE = 0.125f * 1.44269504088896f;  // 1/sqrt(64) * log2(e)
    const int qrow = qstart + 16 * w + c;            // within-batch = position
    const float* qp = qkv + (size_t)(base + qrow) * QKV_DIM + h * HD;
    float x1[8], x2[8];
    *(float4*)&x1[0] = *(const float4*)&qp[8 * g + 0];
    *(float4*)&x1[4] = *(const float4*)&qp[8 * g + 4];
    *(float4*)&x2[0] = *(const float4*)&qp[32 + 8 * g + 0];
    *(float4*)&x2[4] = *(const float4*)&qp[32 + 8 * g + 4];
    bf16x8 qh0, ql0, qh1, ql1;
#pragma unroll
    for (int jj = 0; jj < 8; ++jj) {
        int j = 8 * g + jj;
        float invf = powf(10000.0f, -(float)j / 32.0f);
        float sn, cs;
        sincosf((float)qrow * invf, &sn, &cs);
        float y0 = (x1[jj] * cs - x2[jj] * sn) * SCALE;   // dim j     (kstep 0)
        float y1 = (x2[jj] * cs + x1[jj] * sn) * SCALE;   // dim j+32  (kstep 1)
        ushort_t hh = f2bf(y0);
        qh0[jj] = (short)hh; ql0[jj] = (short)f2bf(y0 - bf2f(hh));
        hh = f2bf(y1);
        qh1[jj] = (short)hh; ql1[jj] = (short)f2bf(y1 - bf2f(hh));
    }

    f32x4 o[4] = {};
    float m[4] = {-1e30f, -1e30f, -1e30f, -1e30f};
    float d[4] = {};

    const int ntiles = L >> 6;
    for (int kt = 0; kt < ntiles; ++kt) {
        const int k0 = kt << 6;
        __syncthreads();  // prior tile's LDS reads done
        // ---- stage: wave w owns array w; 8 chunks of 16B per lane ----
#pragma unroll
        for (int it = 0; it < 8; ++it) {
            int chunk = it * 64 + lane;
            int r = chunk >> 3, s = chunk & 7;          // row, LDS slot
            int gb = s ^ (r & 7);                       // swizzled global block
            if (w < 2) {                                // K arrays: row = key
                const ushort_t* src = (w == 0 ? kh : kl) +
                    (size_t)(base + k0 + r) * DIM + h * HD + 8 * gb;
                ushort8 v = *(const ushort8*)src;
                *(ushort8*)((w == 0 ? sKh : sKl) + r * 64 + 8 * s) = v;
            } else {                                    // V arrays: row = dim
                const ushort_t* src = (w == 2 ? vth : vtl) +
                    (size_t)(h * HD + r) * TOTAL + base + k0 + 8 * gb;
                ushort8 v = *(const ushort8*)src;
                *(ushort8*)((w == 2 ? sVh : sVl) + r * 64 + 8 * s) = v;
            }
        }
        __syncthreads();  // staged tiles visible

        // ---- QK^T: S[16q][64key], 4 key-frags x 2 ksteps x 3 terms ----
        f32x4 sf[4] = {};
#pragma unroll
        for (int f = 0; f < 4; ++f) {
#pragma unroll
            for (int ks = 0; ks < 2; ++ks) {
                int off = (16 * f + c) * 64 + 8 * ((4 * ks + g) ^ (c & 7));
                bf16x8 bh = *(const bf16x8*)&sKh[off];
                bf16x8 bl = *(const bf16x8*)&sKl[off];
                bf16x8 qh = ks ? qh1 : qh0;
                bf16x8 ql = ks ? ql1 : ql0;
                sf[f] = __builtin_amdgcn_mfma_f32_16x16x32_bf16(qh, bh, sf[f], 0, 0, 0);
                sf[f] = __builtin_amdgcn_mfma_f32_16x16x32_bf16(qh, bl, sf[f], 0, 0, 0);
                sf[f] = __builtin_amdgcn_mfma_f32_16x16x32_bf16(ql, bh, sf[f], 0, 0, 0);
            }
        }

        // ---- online softmax (row = 4g+r) + P split/write ----
#pragma unroll
        for (int r = 0; r < 4; ++r) {
            float rm = fmaxf(fmaxf(sf[0][r], sf[1][r]), fmaxf(sf[2][r], sf[3][r]));
            rm = fmaxf(rm, __shfl_xor(rm, 1));
            rm = fmaxf(rm, __shfl_xor(rm, 2));
            rm = fmaxf(rm, __shfl_xor(rm, 4));
            rm = fmaxf(rm, __shfl_xor(rm, 8));
            float mn = fmaxf(m[r], rm);
            float corr = exp2f(m[r] - mn);
            m[r] = mn;
            float p0 = exp2f(sf[0][r] - mn);
            float p1 = exp2f(sf[1][r] - mn);
            float p2 = exp2f(sf[2][r] - mn);
            float p3 = exp2f(sf[3][r] - mn);
            float ps = (p0 + p1) + (p2 + p3);
            ps += __shfl_xor(ps, 1);
            ps += __shfl_xor(ps, 2);
            ps += __shfl_xor(ps, 4);
            ps += __shfl_xor(ps, 8);
            d[r] = d[r] * corr + ps;
            o[0][r] *= corr; o[1][r] *= corr; o[2][r] *= corr; o[3][r] *= corr;
            int ro = (4 * g + r) * 72 + c;
            ushort_t ph;
            ph = f2bf(p0); sPh[w][ro +  0] = ph; sPl[w][ro +  0] = f2bf(p0 - bf2f(ph));
            ph = f2bf(p1); sPh[w][ro + 16] = ph; sPl[w][ro + 16] = f2bf(p1 - bf2f(ph));
            ph = f2bf(p2); sPh[w][ro + 32] = ph; sPl[w][ro + 32] = f2bf(p2 - bf2f(ph));
            ph = f2bf(p3); sPh[w][ro + 48] = ph; sPl[w][ro + 48] = f2bf(p3 - bf2f(ph));
        }
        asm volatile("s_waitcnt lgkmcnt(0)" ::: "memory");  // P writes visible (wave-local)
        __builtin_amdgcn_sched_barrier(0);

        // ---- PV: O[16q][64dim] += P * V ----
#pragma unroll
        for (int ks = 0; ks < 2; ++ks) {
            bf16x8 pah = *(const bf16x8*)&sPh[w][c * 72 + 32 * ks + 8 * g];
            bf16x8 pal = *(const bf16x8*)&sPl[w][c * 72 + 32 * ks + 8 * g];
#pragma unroll
            for (int fd = 0; fd < 4; ++fd) {
                int off = (16 * fd + c) * 64 + 8 * ((4 * ks + g) ^ (c & 7));
                bf16x8 vh = *(const bf16x8*)&sVh[off];
                bf16x8 vl = *(const bf16x8*)&sVl[off];
                o[fd] = __builtin_amdgcn_mfma_f32_16x16x32_bf16(pah, vh, o[fd], 0, 0, 0);
                o[fd] = __builtin_amdgcn_mfma_f32_16x16x32_bf16(pah, vl, o[fd], 0, 0, 0);
                o[fd] = __builtin_amdgcn_mfma_f32_16x16x32_bf16(pal, vh, o[fd], 0, 0, 0);
            }
        }
    }

    // padded keys: score 0 (exp2 domain too), v 0 -> denominator only
    const int npad = MAXLEN - L;
#pragma unroll
    for (int r = 0; r < 4; ++r) {
        float dr = d[r];
        if (npad) dr += (float)npad * exp2f(0.0f - m[r]);
        float inv = 1.0f / dr;
        int row = base + qstart + 16 * w + 4 * g + r;
        float* op = attnb + (size_t)row * DIM + h * HD;
#pragma unroll
        for (int fd = 0; fd < 4; ++fd)
            op[16 * fd + c] = o[fd][r] * inv;
    }
}

// ---------------------------------------------------------------------------
extern "C" void kernel_launch(void* const* d_in, const int* in_sizes, int n_in,
                              void* d_out, int out_size, void* d_ws, size_t ws_size,
                              hipStream_t stream) {
    const float* hidden = (const float*)d_in[0];
    const float* Wqkv = (const float*)d_in[1];
    const float* Wo = (const float*)d_in[2];
    float* out = (float*)d_out;

    const int total = in_sizes[0] / DIM;  // 5120

    // workspace layout (same footprint as round 10, which passed)
    float* qkv = (float*)d_ws;                           // total*3072 f32
    float* attnb = qkv + (size_t)total * QKV_DIM;        // total*1024 f32
    ushort_t* us = (ushort_t*)(attnb + (size_t)total * DIM);
    const size_t nh = (size_t)total * DIM;               // 5.24M
    const size_t nw = (size_t)QKV_DIM * DIM;             // 3.15M
    const size_t no = (size_t)DIM * DIM;                 // 1.05M
    ushort_t* h_hi = us;            ushort_t* h_lo = h_hi + nh;
    ushort_t* wq_hi = h_lo + nh;    ushort_t* wq_lo = wq_hi + nw;
    ushort_t* ao_hi = wq_lo + nw;   ushort_t* ao_lo = ao_hi + nh;
    ushort_t* wo_hi = ao_lo + nh;   ushort_t* wo_lo = wo_hi + no;
    // sequential-use aliases (safe on a single stream):
    ushort_t* kh  = h_hi;    // h splits dead after GEMM1
    ushort_t* kl  = h_lo;
    ushort_t* vth = wq_hi;   // wq splits dead after GEMM1 (2*nw >= nh)
    ushort_t* vtl = ao_hi;   // read by attn; ao_hi written only after attn

    // 0) split inputs
    split_bf16<<<(int)(nh / 4 + 255) / 256, 256, 0, stream>>>(hidden, h_hi, h_lo, (int)(nh / 4));
    split_bf16<<<(int)(nw / 4 + 255) / 256, 256, 0, stream>>>(Wqkv, wq_hi, wq_lo, (int)(nw / 4));
    split_bf16<<<(int)(no / 4 + 255) / 256, 256, 0, stream>>>(Wo, wo_hi, wo_lo, (int)(no / 4));

    // 1) qkv = hidden @ Wqkv^T
    gemm_mfma_split<<<dim3(QKV_DIM / 128, total / 128), 256, 0, stream>>>(
        h_hi, h_lo, wq_hi, wq_lo, qkv, total, QKV_DIM, DIM);

    // 2) K rope+split, V split+transpose
    rope_split_kv<<<dim3(80, NH), 256, 0, stream>>>(qkv, kh, kl, vth, vtl);

    // 3) attention (MFMA) -> attnb
    attn_mfma<<<dim3(80, NH), 256, 0, stream>>>(qkv, kh, kl, vth, vtl, attnb);

    // 4) split attn output, out = attnb @ Wo^T
    split_bf16<<<(int)(nh / 4 + 255) / 256, 256, 0, stream>>>(attnb, ao_hi, ao_lo, (int)(nh / 4));
    gemm_mfma_split<<<dim3(DIM / 128, total / 128), 256, 0, stream>>>(
        ao_hi, ao_lo, wo_hi, wo_lo, out, total, DIM, DIM);
}